// Round 13
// baseline (473.305 us; speedup 1.0000x reference)
//
#include <hip/hip_runtime.h>

// out[b,c] = mask[c] * (U @ X @ U^T),  U[n][h] = sum_k DH2[k][n]*DH[k][h]  (128x64)
// Stage 1: R = X @ U^T   (A = X rows, B = U-frag; R^T stored in LDS as [m][h])
// Stage 2  (transposed): out^T-frag = R^T-frag(A) x U-frag(B) -> D rows=m, cols=n
//          -> 4 contiguous m per lane -> global_store_dwordx4.
// fp16 2-term split (hi+lo), 3 MFMA passes -> ~2^-22 relative error.
// r11: persistent 4-slice blocks (1024 blocks), raw s_barrier + lgkmcnt-only
//      waits (stores NEVER drained in-loop; they overlap next slice's stage-1),
//      X(s+1) prefetch issued before barrier A (consumed at vmcnt(16)),
//      stage-2 U B-frags hoisted out of the slice loop, LDS reads shared
//      across both n-tiles. LDS 36.9KB -> 4 blocks/CU.

typedef __attribute__((ext_vector_type(8))) _Float16 f16x8;
typedef __attribute__((ext_vector_type(4))) _Float16 f16x4;
typedef __attribute__((ext_vector_type(4))) float f32x4;

#define SLICES_PER_BLOCK 4
#define NBLOCKS (4096 / SLICES_PER_BLOCK)
#define MFMA16(A, B, C) __builtin_amdgcn_mfma_f32_16x16x32_f16((A), (B), (C), 0, 0, 0)

// ---------------------------------------------------------------------------
// Build U in MFMA fragment-dump order, fp16 hi/lo (unchanged from r6/r7).
// Fragment (tile j=0..7, kk=0..1, hl=0..1) = 512 halfs; lane l holds 8 halfs:
//   value = U[16*j + (l&15)][32*kk + 8*(l>>4) + t],  t = 0..7
// Serves stage-1 B (by m-tile), stage-2 B (by n-tile) — A/B frag layouts are
// identical on gfx950 16x16x32 (lane -> row/col l&15, k = 8*(l>>4)+t).
// ---------------------------------------------------------------------------
__global__ void build_ut(_Float16* __restrict__ uf) {
    const int idx = blockIdx.x * 256 + threadIdx.x;  // 0..8191
    const int n = idx >> 6;   // 0..127 (U row)
    const int h = idx & 63;   // 0..63  (U col)
    const float s0 = 0.125f;                 // sqrt(1/64)
    const float sk = 0.17677669529663687f;   // sqrt(2/64)
    const float t0 = 0.088388347648318447f;  // sqrt(1/128)
    const float tk = 0.125f;                 // sqrt(2/128)
    float acc = s0 * t0;
    #pragma unroll 4
    for (int k = 1; k < 64; ++k) {
        float a = cospif((float)((2 * h + 1) * k) * (1.0f / 128.0f));
        float b = cospif((float)((2 * n + 1) * k) * (1.0f / 256.0f));
        acc = fmaf(sk * tk * a, b, acc);
    }
    _Float16 hi = (_Float16)acc;
    _Float16 lo = (_Float16)(acc - (float)hi);
    const int j = n >> 4;
    const int lane = (n & 15) + 16 * ((h >> 3) & 3);
    const int kk = h >> 5;
    const int t = h & 7;
    const int base = ((j * 2 + kk) * 2) * 512 + lane * 8 + t;
    uf[base] = hi;         // hl = 0
    uf[base + 512] = lo;   // hl = 1
}

// lgkm-only barrier: prior ds ops visible, global stores stay IN FLIGHT.
__device__ __forceinline__ void barrier_lgkm() {
    __builtin_amdgcn_sched_barrier(0);
    asm volatile("s_waitcnt lgkmcnt(0)" ::: "memory");
    __builtin_amdgcn_s_barrier();
    __builtin_amdgcn_sched_barrier(0);
}

// ---------------------------------------------------------------------------
// One block = 4 consecutive slices. 256 threads = 4 waves.
// Per slice: stage1 (wave wid owns h-tile wid, all 8 m-tiles) -> barrier A ->
// stage2 transposed (wave wid owns n-tiles 2wid,2wid+1; j-outer shares LDS
// reads; dwordx4 stores) -> barrier B (sR reuse guard).
// Stores drain across barriers under the next slice's stage-1/X-load.
// LDS: sRh/sRl [128][72] fp16 = 36.9KB -> 4 blocks/CU.
// ---------------------------------------------------------------------------
__global__ __launch_bounds__(256, 4)
void dct_fsr(const float* __restrict__ x, const float* __restrict__ mask,
             const _Float16* __restrict__ uf, float* __restrict__ out) {
    __shared__ _Float16 sRh[128 * 72];
    __shared__ _Float16 sRl[128 * 72];

    const int tid = threadIdx.x;
    const int wid = tid >> 6;
    const int lane = tid & 63;
    const int l15 = lane & 15;
    const int lg = lane >> 4;  // 0..3
    const int slice0 = blockIdx.x * SLICES_PER_BLOCK;

    const f16x8* ufr = (const f16x8*)uf;  // [frag*64 + lane]

    // ---- stage-2 B-frags (U, n-tiles 2wid & 2wid+1): constant across slices ----
    f16x8 Uh[2][2], Ul[2][2];  // [i][kk]
    #pragma unroll
    for (int i = 0; i < 2; ++i) {
        const int ig = 2 * wid + i;
        #pragma unroll
        for (int kk = 0; kk < 2; ++kk) {
            Uh[i][kk] = ufr[((ig * 2 + kk) * 2 + 0) * 64 + lane];
            Ul[i][kk] = ufr[((ig * 2 + kk) * 2 + 1) * 64 + lane];
        }
    }

    // ---- prologue: issue X(slice0) loads ----
    float4 xa, xb, xc, xd;
    {
        const float* xp = x + (size_t)slice0 * 4096 + (16 * wid + l15) * 64 + 8 * lg;
        xa = *(const float4*)xp;
        xb = *(const float4*)(xp + 4);
        xc = *(const float4*)(xp + 32);
        xd = *(const float4*)(xp + 36);
    }

    for (int s = 0; s < SLICES_PER_BLOCK; ++s) {
        const int slice = slice0 + s;
        const float mval = mask[slice & 255];

        // ---- split X -> fp16 hi/lo A-frags (waits the 4 X loads; outstanding
        //      behind them is only the previous slice's 16 stores -> vmcnt(16)) ----
        f16x8 ah0, al0, ah1, al1;
#define SPLIT(H, L, E, V)                      \
    {                                          \
        float y_ = (V) * mval;                 \
        _Float16 h_ = (_Float16)y_;            \
        H[E] = h_;                             \
        L[E] = (_Float16)(y_ - (float)h_);     \
    }
        SPLIT(ah0, al0, 0, xa.x) SPLIT(ah0, al0, 1, xa.y)
        SPLIT(ah0, al0, 2, xa.z) SPLIT(ah0, al0, 3, xa.w)
        SPLIT(ah0, al0, 4, xb.x) SPLIT(ah0, al0, 5, xb.y)
        SPLIT(ah0, al0, 6, xb.z) SPLIT(ah0, al0, 7, xb.w)
        SPLIT(ah1, al1, 0, xc.x) SPLIT(ah1, al1, 1, xc.y)
        SPLIT(ah1, al1, 2, xc.z) SPLIT(ah1, al1, 3, xc.w)
        SPLIT(ah1, al1, 4, xd.x) SPLIT(ah1, al1, 5, xd.y)
        SPLIT(ah1, al1, 6, xd.z) SPLIT(ah1, al1, 7, xd.w)
#undef SPLIT

        // ---- stage 1: R^T[m][h] into LDS; m-tiles j=0..7 ----
        #pragma unroll
        for (int j = 0; j < 8; ++j) {
            const f16x8 bh0 = ufr[((j * 2 + 0) * 2 + 0) * 64 + lane];
            const f16x8 bl0 = ufr[((j * 2 + 0) * 2 + 1) * 64 + lane];
            const f16x8 bh1 = ufr[((j * 2 + 1) * 2 + 0) * 64 + lane];
            const f16x8 bl1 = ufr[((j * 2 + 1) * 2 + 1) * 64 + lane];
            f32x4 acc = {0.f, 0.f, 0.f, 0.f};
            acc = MFMA16(ah0, bh0, acc);
            acc = MFMA16(ah1, bh1, acc);
            acc = MFMA16(ah0, bl0, acc);
            acc = MFMA16(ah1, bl1, acc);
            acc = MFMA16(al0, bh0, acc);
            acc = MFMA16(al1, bh1, acc);
            // D frag: col m = 16j+l15, rows h = 16*wid + 4*lg + r -> sR[m][h]
            const int m = 16 * j + l15;
            const int h0 = 16 * wid + 4 * lg;
            f16x4 rh, rl;
            #pragma unroll
            for (int r = 0; r < 4; ++r) {
                const float vv = acc[r];
                const _Float16 hi = (_Float16)vv;
                rh[r] = hi;
                rl[r] = (_Float16)(vv - (float)hi);
            }
            *(f16x4*)&sRh[m * 72 + h0] = rh;
            *(f16x4*)&sRl[m * 72 + h0] = rl;
        }

        // ---- issue X(s+1) loads now; consumed after barrier B at vmcnt(16) ----
        if (s + 1 < SLICES_PER_BLOCK) {
            const float* xp =
                x + (size_t)(slice + 1) * 4096 + (16 * wid + l15) * 64 + 8 * lg;
            xa = *(const float4*)xp;
            xb = *(const float4*)(xp + 4);
            xc = *(const float4*)(xp + 32);
            xd = *(const float4*)(xp + 36);
        }

        barrier_lgkm();  // A: sR ready (stores/loads stay in flight)

        // ---- stage 2 (transposed): D rows=m, cols=n; dwordx4 stores ----
        float* og = out + (size_t)slice * 16384;  // 128*128
        #pragma unroll
        for (int j = 0; j < 8; ++j) {
            const int m = 16 * j + l15;
            const f16x8 rh0 = *(const f16x8*)&sRh[m * 72 + 0 + 8 * lg];
            const f16x8 rh1 = *(const f16x8*)&sRh[m * 72 + 32 + 8 * lg];
            const f16x8 rl0 = *(const f16x8*)&sRl[m * 72 + 0 + 8 * lg];
            const f16x8 rl1 = *(const f16x8*)&sRl[m * 72 + 32 + 8 * lg];
            #pragma unroll
            for (int i = 0; i < 2; ++i) {
                f32x4 a = {0.f, 0.f, 0.f, 0.f};
                a = MFMA16(rh0, Uh[i][0], a);
                a = MFMA16(rh1, Uh[i][1], a);
                a = MFMA16(rh0, Ul[i][0], a);
                a = MFMA16(rh1, Ul[i][1], a);
                a = MFMA16(rl0, Uh[i][0], a);
                a = MFMA16(rl1, Uh[i][1], a);
                // D: row m' = 4lg+r (m = 16j+4lg+r), col n = 16*(2wid+i)+l15
                // -> out[n][m]: 4 consecutive m -> one dwordx4
                *(f32x4*)&og[(size_t)(16 * (2 * wid + i) + l15) * 128 + 16 * j +
                             4 * lg] = a;
            }
        }

        barrier_lgkm();  // B: sR reads retired before next stage-1 overwrites
    }
}

extern "C" void kernel_launch(void* const* d_in, const int* in_sizes, int n_in,
                              void* d_out, int out_size, void* d_ws, size_t ws_size,
                              hipStream_t stream) {
    const float* x = (const float*)d_in[0];      // [16,256,64,64] fp32
    const float* mask = (const float*)d_in[1];   // [1,256,1,1] fp32
    float* out = (float*)d_out;                  // [16,256,128,128] fp32
    _Float16* uf = (_Float16*)d_ws;              // 16384 halfs = 32KB

    build_ut<<<32, 256, 0, stream>>>(uf);
    dct_fsr<<<NBLOCKS, 256, 0, stream>>>(x, mask, uf, out);
}